// Round 8
// baseline (539.277 us; speedup 1.0000x reference)
//
#include <hip/hip_runtime.h>
#include <hip/hip_bf16.h>
#include <math.h>

#define EMBED 4096
#define SLEN 2048
#define HEADS 16
#define HDIM 256
#define ROT 64

typedef __bf16 bf16;
typedef __attribute__((ext_vector_type(8))) __bf16 bf16x8;
typedef __attribute__((ext_vector_type(4))) float f32x4;

__device__ __forceinline__ void async_copy16(const void* g, void* l) {
  __builtin_amdgcn_global_load_lds((const __attribute__((address_space(1))) void*)g,
                                   (__attribute__((address_space(3))) void*)l,
                                   16, 0, 0);
}

// ---------------- cast fp32 -> bf16 ----------------
__global__ __launch_bounds__(256) void cast_kernel(const float* __restrict__ in,
                                                   bf16* __restrict__ out, int n4) {
  int i = blockIdx.x * 256 + threadIdx.x;
  if (i >= n4) return;
  float4 v = ((const float4*)in)[i];
  bf16 o[4] __attribute__((aligned(8)));
  o[0] = (bf16)v.x; o[1] = (bf16)v.y; o[2] = (bf16)v.z; o[3] = (bf16)v.w;
  ((ushort4*)out)[i] = *(const ushort4*)o;
}

// ---------------- transpose + cast: Wt[n][k] = W[k][n] ----------------
__global__ __launch_bounds__(256) void transpose_cast(const float* __restrict__ W,
                                                      bf16* __restrict__ Wt) {
  __shared__ bf16 tile[64][65];
  int k0 = blockIdx.y * 64, n0 = blockIdx.x * 64;
  int tr = threadIdx.x >> 4, tc = threadIdx.x & 15;
#pragma unroll
  for (int i = 0; i < 4; i++) {
    int row = tr + i * 16;
    float4 v = *(const float4*)(W + (size_t)(k0 + row) * EMBED + n0 + tc * 4);
    tile[row][tc * 4 + 0] = (bf16)v.x;
    tile[row][tc * 4 + 1] = (bf16)v.y;
    tile[row][tc * 4 + 2] = (bf16)v.z;
    tile[row][tc * 4 + 3] = (bf16)v.w;
  }
  __syncthreads();
#pragma unroll
  for (int i = 0; i < 4; i++) {
    int nl = tr + i * 16;
    bf16 o[4] __attribute__((aligned(8)));
#pragma unroll
    for (int j = 0; j < 4; j++) o[j] = tile[tc * 4 + j][nl];
    *(ushort4*)(Wt + (size_t)(n0 + nl) * EMBED + k0 + tc * 4) = *(const ushort4*)o;
  }
}

// ---------------- pipelined GEMM: C[M,N] = A[M,K] * Bt[N,K]^T (bf16 in) -------
// (R7-proven; unchanged this round.)
template <int MODE>
__global__ __launch_bounds__(512, 1) void gemm_pipe(const bf16* __restrict__ A,
                                                    const bf16* __restrict__ Bt,
                                                    void* __restrict__ Cout,
                                                    int M, int N, int K) {
  constexpr int BM = 128, BN = 256, BK = 64;
  __shared__ __align__(16) bf16 As[3][BM * BK];  // 3 x 16 KB
  __shared__ __align__(16) bf16 Bs[3][BN * BK];  // 3 x 32 KB
  int t = threadIdx.x;
  int lane = t & 63, w = t >> 6;
  int c16 = lane & 15, g4 = lane >> 4;
  int wm = w >> 2, wn = w & 3;
  int m0 = blockIdx.y * BM, n0 = blockIdx.x * BN;
  int nt = K / BK;

  f32x4 acc[4][4] = {};

  auto stageA1 = [&](const bf16* Asrc, bf16* Ad, int i) {
    int c = i * 512 + t;
    int row = c >> 3, col8 = c & 7;
    async_copy16(Asrc + (size_t)row * K + ((col8 ^ (row & 7)) * 8), Ad + c * 8);
  };
  auto stageB1 = [&](const bf16* Bsrc, bf16* Bd, int i) {
    int c = i * 512 + t;
    int row = c >> 3, col8 = c & 7;
    async_copy16(Bsrc + (size_t)row * K + ((col8 ^ (row & 7)) * 8), Bd + c * 8);
  };

  // prologue: tiles 0 and 1 fully in flight; wait tile 0 (6 of 12 remain)
#pragma unroll
  for (int kt0 = 0; kt0 < 2; kt0++) {
    const bf16* Asrc = A + (size_t)m0 * K + kt0 * BK;
    const bf16* Bsrc = Bt + (size_t)n0 * K + kt0 * BK;
#pragma unroll
    for (int i = 0; i < 2; i++) stageA1(Asrc, As[kt0], i);
#pragma unroll
    for (int i = 0; i < 4; i++) stageB1(Bsrc, Bs[kt0], i);
  }
  asm volatile("s_waitcnt vmcnt(6)" ::: "memory");
  __builtin_amdgcn_s_barrier();

  for (int kt = 0; kt < nt; kt++) {
    int slot = kt - (kt / 3) * 3;
    int s2 = (kt + 2) - ((kt + 2) / 3) * 3;
    const bf16* Ab = As[slot];
    const bf16* Bb = Bs[slot];
    bool do_stage = (kt + 2 < nt);
    const bf16* Asrc = A + (size_t)m0 * K + (kt + 2) * BK;
    const bf16* Bsrc = Bt + (size_t)n0 * K + (kt + 2) * BK;
    bf16* Ad = As[s2];
    bf16* Bd = Bs[s2];

    // ================= phase 0 (kk=0) =================
    {
      bf16x8 af[4], bfr[4];
#pragma unroll
      for (int fm = 0; fm < 4; fm++) {
        int row = wm * 64 + fm * 16 + c16;
        af[fm] = *(const bf16x8*)(Ab + row * BK + ((g4 ^ (row & 7)) * 8));
      }
#pragma unroll
      for (int fn = 0; fn < 4; fn++) {
        int row = wn * 64 + fn * 16 + c16;
        bfr[fn] = *(const bf16x8*)(Bb + row * BK + ((g4 ^ (row & 7)) * 8));
      }
      if (do_stage) {
        stageA1(Asrc, Ad, 0);
        stageA1(Asrc, Ad, 1);
        stageB1(Bsrc, Bd, 0);
        stageB1(Bsrc, Bd, 1);
      }
      __builtin_amdgcn_s_barrier();
      asm volatile("s_waitcnt lgkmcnt(0)" ::: "memory");
      __builtin_amdgcn_sched_barrier(0);
      __builtin_amdgcn_s_setprio(1);
#pragma unroll
      for (int fm = 0; fm < 4; fm++)
#pragma unroll
        for (int fn = 0; fn < 4; fn++)
          acc[fm][fn] = __builtin_amdgcn_mfma_f32_16x16x32_bf16(af[fm], bfr[fn],
                                                                acc[fm][fn], 0, 0, 0);
      __builtin_amdgcn_s_setprio(0);
      __builtin_amdgcn_s_barrier();
    }
    // ================= phase 1 (kk=1) =================
    {
      bf16x8 af[4], bfr[4];
#pragma unroll
      for (int fm = 0; fm < 4; fm++) {
        int row = wm * 64 + fm * 16 + c16;
        af[fm] = *(const bf16x8*)(Ab + row * BK + (((4 + g4) ^ (row & 7)) * 8));
      }
#pragma unroll
      for (int fn = 0; fn < 4; fn++) {
        int row = wn * 64 + fn * 16 + c16;
        bfr[fn] = *(const bf16x8*)(Bb + row * BK + (((4 + g4) ^ (row & 7)) * 8));
      }
      if (do_stage) {
        stageB1(Bsrc, Bd, 2);
        stageB1(Bsrc, Bd, 3);
      }
      __builtin_amdgcn_s_barrier();
      asm volatile("s_waitcnt lgkmcnt(0)" ::: "memory");
      __builtin_amdgcn_sched_barrier(0);
      __builtin_amdgcn_s_setprio(1);
#pragma unroll
      for (int fm = 0; fm < 4; fm++)
#pragma unroll
        for (int fn = 0; fn < 4; fn++)
          acc[fm][fn] = __builtin_amdgcn_mfma_f32_16x16x32_bf16(af[fm], bfr[fn],
                                                                acc[fm][fn], 0, 0, 0);
      __builtin_amdgcn_s_setprio(0);
      if (kt < nt - 2) {
        asm volatile("s_waitcnt vmcnt(6)" ::: "memory");
      } else if (kt == nt - 2) {
        asm volatile("s_waitcnt vmcnt(0)" ::: "memory");
      }
      __builtin_amdgcn_s_barrier();
    }
  }

  // epilogue
#pragma unroll
  for (int fm = 0; fm < 4; fm++) {
#pragma unroll
    for (int fn = 0; fn < 4; fn++) {
      int col = n0 + wn * 64 + fn * 16 + c16;
#pragma unroll
      for (int r = 0; r < 4; r++) {
        int row = m0 + wm * 64 + fm * 16 + g4 * 4 + r;
        float v = acc[fm][fn][r];
        if (MODE == 1) {
          int d = col & (HDIM - 1);
          if (d < ROT) {  // wave-uniform: true iff wn==0
            float pv = __shfl_xor(v, 1);
            int jj = d >> 1;
            float invf = __expf(-0.28782313662425575f * (float)jj);
            float ang = (float)row * invf;
            float sa, ca;
            sincosf(ang, &sa, &ca);
            v = v * ca + pv * sa;  // reference has NO negation in rotate_every_two
          }
        }
        if (MODE == 3) {
          ((float*)Cout)[(size_t)row * N + col] = v;
        } else if (MODE == 2) {
          ((bf16*)Cout)[(size_t)col * M + row] = (bf16)v;
        } else {
          ((bf16*)Cout)[(size_t)row * N + col] = (bf16)v;
        }
      }
    }
  }
}

// ---------------- causal flash attention (8-wave QBLK=128, 2 waves/SIMD) ------
// Q,K: [S,H*D] bf16 (rotary applied). Vt: [(h,d), S] bf16. O: [S,H*D] bf16.
// 256 blocks = 16 heads x 16 q-tiles of 128 rows; 512 threads = 8 waves, each
// wave owns 16 q-rows (identical inner machinery to the proven 4-wave kernel).
// LPT order: qt = 15-(b>>4) (heavy blocks dispatch first); h = b&15 gives each
// XCD ~2 heads (K+V = 4 MB = one L2). K,V double-buffered (KVBLK=64); LDS
// 144 KB -> 1 block/CU but 2 waves/SIMD (TLP hides ds_read/exp latency that
// capped the 4-wave version at 1 wave/SIMD). Per-wave `active` gate skips
// fully-masked tiles; diag mask uses global indices. defer-max (T13, THR=8).
__global__ __launch_bounds__(512, 1) void attn_kernel(const bf16* __restrict__ Q,
                                                      const bf16* __restrict__ Kmat,
                                                      const bf16* __restrict__ Vt,
                                                      bf16* __restrict__ O) {
  __shared__ __align__(16) bf16 Ks[2][64 * 256];   // [kv_row][d], swizzled (64 KB)
  __shared__ __align__(16) bf16 Vs[2][64 * 256];   // [d][kv_row], swizzled (64 KB)
  __shared__ __align__(16) bf16 Pl[8][16 * 64];    // per-wave P, swizzled (16 KB)
  int t = threadIdx.x, lane = t & 63, w = t >> 6;
  int c16 = lane & 15, g4 = lane >> 4;
  int b = blockIdx.x;
  int h = b & 15;
  int qt = 15 - (b >> 4);       // LPT: heavy q-tiles first
  int q0w = qt * 128 + w * 16;  // this wave's first q-row
  int ktmax = 2 * qt + 1;       // inclusive; KV tiles of 64 rows

  bf16x8 qf[8];
  {
    const bf16* qp = Q + (size_t)(q0w + c16) * EMBED + h * HDIM + g4 * 8;
#pragma unroll
    for (int kk = 0; kk < 8; kk++) qf[kk] = *(const bf16x8*)(qp + kk * 32);
  }
  f32x4 acco[16] = {};
  float mrow[4], lrow[4];
#pragma unroll
  for (int r = 0; r < 4; r++) { mrow[r] = -1e30f; lrow[r] = 0.f; }

  // prologue: stage tile 0 -> buffer 0 (K: 2048 chunks, V: 2048 chunks / 512 thr)
#pragma unroll
  for (int j = 0; j < 4; j++) {
    int c = j * 512 + t;
    int row = c >> 5, col8 = c & 31;
    async_copy16(Kmat + (size_t)row * EMBED + h * HDIM + ((col8 ^ (row & 7)) * 8),
                 Ks[0] + (size_t)c * 8);
  }
#pragma unroll
  for (int j = 0; j < 4; j++) {
    int c = j * 512 + t;
    int row = c >> 3, col8 = c & 7;
    async_copy16(Vt + (size_t)(h * HDIM + row) * SLEN + ((col8 ^ (row & 7)) * 8),
                 Vs[0] + (size_t)c * 8);
  }
  __syncthreads();  // drain vmcnt(0): tile 0 resident

  for (int kt = 0; kt <= ktmax; kt++) {
    int cur = kt & 1;
    if (kt < ktmax) {  // prefetch tile kt+1 into the other buffer
#pragma unroll
      for (int j = 0; j < 4; j++) {
        int c = j * 512 + t;
        int row = c >> 5, col8 = c & 31;
        async_copy16(Kmat + (size_t)((kt + 1) * 64 + row) * EMBED + h * HDIM +
                         ((col8 ^ (row & 7)) * 8),
                     Ks[cur ^ 1] + (size_t)c * 8);
      }
#pragma unroll
      for (int j = 0; j < 4; j++) {
        int c = j * 512 + t;
        int row = c >> 3, col8 = c & 7;
        async_copy16(Vt + (size_t)(h * HDIM + row) * SLEN + (kt + 1) * 64 +
                         ((col8 ^ (row & 7)) * 8),
                     Vs[cur ^ 1] + (size_t)c * 8);
      }
    }
    // wave-uniform: skip tiles entirely above this wave's rows (fully masked)
    bool active = (kt * 64 <= q0w + 15);
    if (active) {
      const bf16* KsB = Ks[cur];
      const bf16* VsB = Vs[cur];

      f32x4 accs[4] = {};
      __builtin_amdgcn_s_setprio(1);
#pragma unroll
      for (int kk = 0; kk < 8; kk++) {
#pragma unroll
        for (int fn = 0; fn < 4; fn++) {
          int r = fn * 16 + c16;
          bf16x8 kf = *(const bf16x8*)(KsB + r * 256 + ((kk * 4 + g4) ^ (c16 & 7)) * 8);
          accs[fn] = __builtin_amdgcn_mfma_f32_16x16x32_bf16(qf[kk], kf, accs[fn], 0, 0, 0);
        }
      }
      __builtin_amdgcn_s_setprio(0);

      float pm[4][4];
      bool diag = (kt * 64 + 63 > q0w);  // some kg may exceed some qg
#pragma unroll
      for (int fn = 0; fn < 4; fn++)
#pragma unroll
        for (int r = 0; r < 4; r++) {
          float s = accs[fn][r] * 0.0625f;  // 1/sqrt(256); mask-before-scale == -1e30
          if (diag) {
            int kg = kt * 64 + fn * 16 + c16;
            int qg = q0w + g4 * 4 + r;
            if (kg > qg) s = -1e30f;
          }
          pm[fn][r] = s;
        }
      float tmx[4];
#pragma unroll
      for (int r = 0; r < 4; r++) {
        float mx = fmaxf(fmaxf(pm[0][r], pm[1][r]), fmaxf(pm[2][r], pm[3][r]));
#pragma unroll
        for (int off = 1; off < 16; off <<= 1) mx = fmaxf(mx, __shfl_xor(mx, off));
        tmx[r] = mx;
      }
      bool need = false;
#pragma unroll
      for (int r = 0; r < 4; r++) need = need || (tmx[r] > mrow[r] + 8.0f);
      if (__any(need)) {
#pragma unroll
        for (int r = 0; r < 4; r++) {
          float mn = fmaxf(mrow[r], tmx[r]);
          float sc = __expf(mrow[r] - mn);
          mrow[r] = mn;
          lrow[r] *= sc;
#pragma unroll
          for (int fd = 0; fd < 16; fd++) acco[fd][r] *= sc;
        }
      }
      float rs[4] = {0.f, 0.f, 0.f, 0.f};
#pragma unroll
      for (int fn = 0; fn < 4; fn++)
#pragma unroll
        for (int r = 0; r < 4; r++) {
          float p = __expf(pm[fn][r] - mrow[r]);
          pm[fn][r] = p;
          rs[r] += p;
        }
#pragma unroll
      for (int r = 0; r < 4; r++) {
#pragma unroll
        for (int off = 1; off < 16; off <<= 1) rs[r] += __shfl_xor(rs[r], off);
        lrow[r] += rs[r];
      }
      // Pl write (per-wave buffer; same-wave RAW handled by lgkmcnt)
#pragma unroll
      for (int fn = 0; fn < 4; fn++)
#pragma unroll
        for (int r = 0; r < 4; r++) {
          int q = g4 * 4 + r;
          int chunk = (fn * 2 + (c16 >> 3)) ^ (q & 7);
          Pl[w][q * 64 + chunk * 8 + (c16 & 7)] = (bf16)pm[fn][r];
        }
      __builtin_amdgcn_s_setprio(1);
#pragma unroll
      for (int kk2 = 0; kk2 < 2; kk2++) {
        bf16x8 pf = *(const bf16x8*)(&Pl[w][c16 * 64 + ((kk2 * 4 + g4) ^ (c16 & 7)) * 8]);
#pragma unroll
        for (int fd = 0; fd < 16; fd++) {
          int rv = fd * 16 + c16;
          bf16x8 vf = *(const bf16x8*)(VsB + rv * 64 + ((kk2 * 4 + g4) ^ (c16 & 7)) * 8);
          acco[fd] = __builtin_amdgcn_mfma_f32_16x16x32_bf16(pf, vf, acco[fd], 0, 0, 0);
        }
      }
      __builtin_amdgcn_s_setprio(0);
    }
    // one barrier/iter: drains prefetch (implicit vmcnt 0) + protects swap
    __syncthreads();
  }
  float inv[4];
#pragma unroll
  for (int r = 0; r < 4; r++) inv[r] = 1.0f / lrow[r];
#pragma unroll
  for (int fd = 0; fd < 16; fd++)
#pragma unroll
    for (int r = 0; r < 4; r++) {
      int qg = q0w + g4 * 4 + r;
      int col = h * HDIM + fd * 16 + c16;
      O[(size_t)qg * EMBED + col] = (bf16)(acco[fd][r] * inv[r]);
    }
}

extern "C" void kernel_launch(void* const* d_in, const int* in_sizes, int n_in,
                              void* d_out, int out_size, void* d_ws, size_t ws_size,
                              hipStream_t stream) {
  const float* hidden = (const float*)d_in[0];
  const float* Wq = (const float*)d_in[1];
  const float* Wk = (const float*)d_in[2];
  const float* Wv = (const float*)d_in[3];
  const float* Wo = (const float*)d_in[4];
  float* out = (float*)d_out;

  char* ws = (char*)d_ws;
  const size_t SZ_H = (size_t)SLEN * EMBED * 2;   // 16 MiB
  const size_t SZ_W = (size_t)EMBED * EMBED * 2;  // 32 MiB
  if (ws_size < 5 * SZ_H + SZ_W) return;

  bf16* h_bf = (bf16*)ws;
  bf16* Wt   = (bf16*)(ws + SZ_H);
  bf16* Qb   = (bf16*)(ws + SZ_H + SZ_W);
  bf16* Kb   = (bf16*)(ws + 2 * SZ_H + SZ_W);
  bf16* Vtb  = (bf16*)(ws + 3 * SZ_H + SZ_W);
  bf16* Ob   = (bf16*)(ws + 4 * SZ_H + SZ_W);

  cast_kernel<<<(SLEN * EMBED / 4 + 255) / 256, 256, 0, stream>>>(hidden, h_bf,
                                                                  SLEN * EMBED / 4);

  dim3 tgrid(EMBED / 64, EMBED / 64);
  dim3 ggrid(EMBED / 256, SLEN / 128);  // 16 x 16 = 256 blocks

  transpose_cast<<<tgrid, 256, 0, stream>>>(Wq, Wt);
  gemm_pipe<1><<<ggrid, 512, 0, stream>>>(h_bf, Wt, Qb, SLEN, EMBED, EMBED);

  transpose_cast<<<tgrid, 256, 0, stream>>>(Wk, Wt);
  gemm_pipe<1><<<ggrid, 512, 0, stream>>>(h_bf, Wt, Kb, SLEN, EMBED, EMBED);

  transpose_cast<<<tgrid, 256, 0, stream>>>(Wv, Wt);
  gemm_pipe<2><<<ggrid, 512, 0, stream>>>(h_bf, Wt, Vtb, SLEN, EMBED, EMBED);

  attn_kernel<<<dim3(256), 512, 0, stream>>>(Qb, Kb, Vtb, Ob);

  transpose_cast<<<tgrid, 256, 0, stream>>>(Wo, Wt);
  gemm_pipe<3><<<ggrid, 512, 0, stream>>>(Ob, Wt, out, SLEN, EMBED, EMBED);
}

// Round 9
// 480.622 us; speedup vs baseline: 1.1220x; 1.1220x over previous
//
#include <hip/hip_runtime.h>
#include <hip/hip_bf16.h>
#include <math.h>

#define EMBED 4096
#define SLEN 2048
#define HEADS 16
#define HDIM 256
#define ROT 64

typedef __bf16 bf16;
typedef __attribute__((ext_vector_type(8))) __bf16 bf16x8;
typedef __attribute__((ext_vector_type(4))) float f32x4;

__device__ __forceinline__ void async_copy16(const void* g, void* l) {
  __builtin_amdgcn_global_load_lds((const __attribute__((address_space(1))) void*)g,
                                   (__attribute__((address_space(3))) void*)l,
                                   16, 0, 0);
}

// ---------------- cast fp32 -> bf16 ----------------
__global__ __launch_bounds__(256) void cast_kernel(const float* __restrict__ in,
                                                   bf16* __restrict__ out, int n4) {
  int i = blockIdx.x * 256 + threadIdx.x;
  if (i >= n4) return;
  float4 v = ((const float4*)in)[i];
  bf16 o[4] __attribute__((aligned(8)));
  o[0] = (bf16)v.x; o[1] = (bf16)v.y; o[2] = (bf16)v.z; o[3] = (bf16)v.w;
  ((ushort4*)out)[i] = *(const ushort4*)o;
}

// ---------------- transpose + cast: Wt[n][k] = W[k][n] ----------------
__global__ __launch_bounds__(256) void transpose_cast(const float* __restrict__ W,
                                                      bf16* __restrict__ Wt) {
  __shared__ bf16 tile[64][65];
  int k0 = blockIdx.y * 64, n0 = blockIdx.x * 64;
  int tr = threadIdx.x >> 4, tc = threadIdx.x & 15;
#pragma unroll
  for (int i = 0; i < 4; i++) {
    int row = tr + i * 16;
    float4 v = *(const float4*)(W + (size_t)(k0 + row) * EMBED + n0 + tc * 4);
    tile[row][tc * 4 + 0] = (bf16)v.x;
    tile[row][tc * 4 + 1] = (bf16)v.y;
    tile[row][tc * 4 + 2] = (bf16)v.z;
    tile[row][tc * 4 + 3] = (bf16)v.w;
  }
  __syncthreads();
#pragma unroll
  for (int i = 0; i < 4; i++) {
    int nl = tr + i * 16;
    bf16 o[4] __attribute__((aligned(8)));
#pragma unroll
    for (int j = 0; j < 4; j++) o[j] = tile[tc * 4 + j][nl];
    *(ushort4*)(Wt + (size_t)(n0 + nl) * EMBED + k0 + tc * 4) = *(const ushort4*)o;
  }
}

// ---------------- pipelined GEMM: C[M,N] = A[M,K] * Bt[N,K]^T (bf16 in) -------
// BM=128, BN=256, BK=64; 512 threads = 8 waves (2M x 4N), 64x64 per wave.
// Triple-buffered LDS (144 KB), prefetch depth 2 via global_load_lds.
// ONE barrier per K-tile: {read all 16 frags; stage(kt+2); MFMA kk0 (kk1 reads
// overlap via compiler's counted lgkmcnt); MFMA kk1; vmcnt(6); s_barrier}.
// The LDS pipe never idles behind a barrier during MFMA (it was 4 barriers/tile
// before). Counted vmcnt never drains in steady state (T3+T4). XOR-swizzle (T2,
// conflicts=0 measured). MODE 1: rotary out (Q,K); 2: V-transposed; 3: fp32.
template <int MODE>
__global__ __launch_bounds__(512, 1) void gemm_pipe(const bf16* __restrict__ A,
                                                    const bf16* __restrict__ Bt,
                                                    void* __restrict__ Cout,
                                                    int M, int N, int K) {
  constexpr int BM = 128, BN = 256, BK = 64;
  __shared__ __align__(16) bf16 As[3][BM * BK];  // 3 x 16 KB
  __shared__ __align__(16) bf16 Bs[3][BN * BK];  // 3 x 32 KB
  int t = threadIdx.x;
  int lane = t & 63, w = t >> 6;
  int c16 = lane & 15, g4 = lane >> 4;
  int wm = w >> 2, wn = w & 3;
  int m0 = blockIdx.y * BM, n0 = blockIdx.x * BN;
  int nt = K / BK;

  f32x4 acc[4][4] = {};

  auto stage = [&](int kt, int slot) {
    const bf16* Asrc = A + (size_t)m0 * K + kt * BK;
    const bf16* Bsrc = Bt + (size_t)n0 * K + kt * BK;
    bf16* Ad = As[slot];
    bf16* Bd = Bs[slot];
#pragma unroll
    for (int i = 0; i < 2; i++) {  // A: 1024 chunks / 512 threads
      int c = i * 512 + t;
      int row = c >> 3, col8 = c & 7;
      async_copy16(Asrc + (size_t)row * K + ((col8 ^ (row & 7)) * 8), Ad + c * 8);
    }
#pragma unroll
    for (int i = 0; i < 4; i++) {  // B: 2048 chunks / 512 threads
      int c = i * 512 + t;
      int row = c >> 3, col8 = c & 7;
      async_copy16(Bsrc + (size_t)row * K + ((col8 ^ (row & 7)) * 8), Bd + c * 8);
    }
  };

  // prologue: tiles 0 and 1 in flight; wait tile 0 (6 of 12 outstanding left)
  stage(0, 0);
  stage(1, 1);
  asm volatile("s_waitcnt vmcnt(6)" ::: "memory");
  __builtin_amdgcn_s_barrier();

  for (int kt = 0; kt < nt; kt++) {
    int slot = kt - (kt / 3) * 3;
    const bf16* Ab = As[slot];
    const bf16* Bb = Bs[slot];

    // issue ALL fragment reads for this tile up front (kk0 then kk1); the
    // compiler's counted lgkmcnt lets kk1's reads complete under kk0's MFMAs.
    bf16x8 af[2][4], bfr[2][4];
#pragma unroll
    for (int kk = 0; kk < 2; kk++) {
#pragma unroll
      for (int fm = 0; fm < 4; fm++) {
        int row = wm * 64 + fm * 16 + c16;
        af[kk][fm] = *(const bf16x8*)(Ab + row * BK + (((kk * 4 + g4) ^ (row & 7)) * 8));
      }
#pragma unroll
      for (int fn = 0; fn < 4; fn++) {
        int row = wn * 64 + fn * 16 + c16;
        bfr[kk][fn] = *(const bf16x8*)(Bb + row * BK + (((kk * 4 + g4) ^ (row & 7)) * 8));
      }
    }
    if (kt + 2 < nt) {
      int s2 = (kt + 2) - ((kt + 2) / 3) * 3;
      stage(kt + 2, s2);
    }
    __builtin_amdgcn_s_setprio(1);
#pragma unroll
    for (int kk = 0; kk < 2; kk++)
#pragma unroll
      for (int fm = 0; fm < 4; fm++)
#pragma unroll
        for (int fn = 0; fn < 4; fn++)
          acc[fm][fn] = __builtin_amdgcn_mfma_f32_16x16x32_bf16(af[kk][fm], bfr[kk][fn],
                                                                acc[fm][fn], 0, 0, 0);
    __builtin_amdgcn_s_setprio(0);
    // end-of-tile sync: tile kt+1 must be resident; tile kt+2 stays in flight.
    // (All this wave's ds_reads completed before its last MFMA issued, so the
    // barrier also guarantees no wave still reads the slot stage() targets next.)
    if (kt < nt - 2) {
      asm volatile("s_waitcnt vmcnt(6)" ::: "memory");
      __builtin_amdgcn_s_barrier();
    } else if (kt == nt - 2) {
      asm volatile("s_waitcnt vmcnt(0)" ::: "memory");
      __builtin_amdgcn_s_barrier();
    }
  }

  // epilogue
#pragma unroll
  for (int fm = 0; fm < 4; fm++) {
#pragma unroll
    for (int fn = 0; fn < 4; fn++) {
      int col = n0 + wn * 64 + fn * 16 + c16;
#pragma unroll
      for (int r = 0; r < 4; r++) {
        int row = m0 + wm * 64 + fm * 16 + g4 * 4 + r;
        float v = acc[fm][fn][r];
        if (MODE == 1) {
          int d = col & (HDIM - 1);
          if (d < ROT) {  // wave-uniform: true iff wn==0
            float pv = __shfl_xor(v, 1);
            int jj = d >> 1;
            float invf = __expf(-0.28782313662425575f * (float)jj);
            float ang = (float)row * invf;
            float sa, ca;
            sincosf(ang, &sa, &ca);
            v = v * ca + pv * sa;  // reference has NO negation in rotate_every_two
          }
        }
        if (MODE == 3) {
          ((float*)Cout)[(size_t)row * N + col] = v;
        } else if (MODE == 2) {
          ((bf16*)Cout)[(size_t)col * M + row] = (bf16)v;
        } else {
          ((bf16*)Cout)[(size_t)row * N + col] = (bf16)v;
        }
      }
    }
  }
}

// ---------------- causal flash attention (R4/R7-proven, reverted verbatim) ----
// 256 blocks, 1/CU (136 KB LDS). head=(b&7)*2+((b>>3)&1) (2 heads/XCD -> K+V
// = 4 MB = one L2), pair=b>>4; passes qt=pair then 31-pair -> exactly 33
// kt-iterations/block (perfect balance). K,V double-buffered; prefetch issued
// before compute; one barrier/iter. XOR-swizzled LDS. defer-max (T13, THR=8).
__global__ __launch_bounds__(256, 1) void attn_kernel(const bf16* __restrict__ Q,
                                                      const bf16* __restrict__ Kmat,
                                                      const bf16* __restrict__ Vt,
                                                      bf16* __restrict__ O) {
  __shared__ __align__(16) bf16 Ks[2][64 * 256];   // [kv_row][d], swizzled
  __shared__ __align__(16) bf16 Vs[2][64 * 256];   // [d][kv_row], swizzled
  __shared__ __align__(16) bf16 Pl[4][16 * 64];    // per-wave P, swizzled
  int t = threadIdx.x, lane = t & 63, w = t >> 6;
  int c16 = lane & 15, g4 = lane >> 4;
  int b = blockIdx.x;
  int h = (b & 7) * 2 + ((b >> 3) & 1);
  int pair = b >> 4;

  for (int pass = 0; pass < 2; ++pass) {
    int qt = pass ? (31 - pair) : pair;
    int q0w = qt * 64 + w * 16;

    bf16x8 qf[8];
    {
      const bf16* qp = Q + (size_t)(q0w + c16) * EMBED + h * HDIM + g4 * 8;
#pragma unroll
      for (int kk = 0; kk < 8; kk++) qf[kk] = *(const bf16x8*)(qp + kk * 32);
    }
    f32x4 acco[16] = {};
    float mrow[4], lrow[4];
#pragma unroll
    for (int r = 0; r < 4; r++) { mrow[r] = -1e30f; lrow[r] = 0.f; }

    __syncthreads();
#pragma unroll
    for (int j = 0; j < 8; j++) {
      int c = j * 256 + w * 64 + lane;
      int row = c >> 5, col8 = c & 31;
      int scol = (col8 ^ (row & 7)) * 8;
      async_copy16(Kmat + (size_t)(0 * 64 + row) * EMBED + h * HDIM + scol,
                   Ks[0] + (size_t)c * 8);
    }
#pragma unroll
    for (int j = 0; j < 8; j++) {
      int c = j * 256 + w * 64 + lane;
      int row = c >> 3, col8 = c & 7;
      int scol = (col8 ^ (row & 7)) * 8;
      async_copy16(Vt + (size_t)(h * HDIM + row) * SLEN + 0 * 64 + scol,
                   Vs[0] + (size_t)c * 8);
    }
    __syncthreads();

    for (int kt = 0; kt <= qt; kt++) {
      int cur = kt & 1;
      if (kt < qt) {
#pragma unroll
        for (int j = 0; j < 8; j++) {
          int c = j * 256 + w * 64 + lane;
          int row = c >> 5, col8 = c & 31;
          int scol = (col8 ^ (row & 7)) * 8;
          async_copy16(Kmat + (size_t)((kt + 1) * 64 + row) * EMBED + h * HDIM + scol,
                       Ks[cur ^ 1] + (size_t)c * 8);
        }
#pragma unroll
        for (int j = 0; j < 8; j++) {
          int c = j * 256 + w * 64 + lane;
          int row = c >> 3, col8 = c & 7;
          int scol = (col8 ^ (row & 7)) * 8;
          async_copy16(Vt + (size_t)(h * HDIM + row) * SLEN + (kt + 1) * 64 + scol,
                       Vs[cur ^ 1] + (size_t)c * 8);
        }
      }
      const bf16* KsB = Ks[cur];
      const bf16* VsB = Vs[cur];

      f32x4 accs[4] = {};
      __builtin_amdgcn_s_setprio(1);
#pragma unroll
      for (int kk = 0; kk < 8; kk++) {
#pragma unroll
        for (int fn = 0; fn < 4; fn++) {
          int r = fn * 16 + c16;
          bf16x8 kf = *(const bf16x8*)(KsB + r * 256 + ((kk * 4 + g4) ^ (c16 & 7)) * 8);
          accs[fn] = __builtin_amdgcn_mfma_f32_16x16x32_bf16(qf[kk], kf, accs[fn], 0, 0, 0);
        }
      }
      __builtin_amdgcn_s_setprio(0);

      float pm[4][4];
      bool diag = (kt == qt);
#pragma unroll
      for (int fn = 0; fn < 4; fn++)
#pragma unroll
        for (int r = 0; r < 4; r++) {
          float s = accs[fn][r] * 0.0625f;  // 1/sqrt(256); mask-before-scale == -1e30
          if (diag) {
            int kg = fn * 16 + c16;
            int qg = w * 16 + g4 * 4 + r;
            if (kg > qg) s = -1e30f;
          }
          pm[fn][r] = s;
        }
      float tmx[4];
#pragma unroll
      for (int r = 0; r < 4; r++) {
        float mx = fmaxf(fmaxf(pm[0][r], pm[1][r]), fmaxf(pm[2][r], pm[3][r]));
#pragma unroll
        for (int off = 1; off < 16; off <<= 1) mx = fmaxf(mx, __shfl_xor(mx, off));
        tmx[r] = mx;
      }
      bool need = false;
#pragma unroll
      for (int r = 0; r < 4; r++) need = need || (tmx[r] > mrow[r] + 8.0f);
      if (__any(need)) {
#pragma unroll
        for (int r = 0; r < 4; r++) {
          float mn = fmaxf(mrow[r], tmx[r]);
          float sc = __expf(mrow[r] - mn);
          mrow[r] = mn;
          lrow[r] *= sc;
#pragma unroll
          for (int fd = 0; fd < 16; fd++) acco[fd][r] *= sc;
        }
      }
      float rs[4] = {0.f, 0.f, 0.f, 0.f};
#pragma unroll
      for (int fn = 0; fn < 4; fn++)
#pragma unroll
        for (int r = 0; r < 4; r++) {
          float p = __expf(pm[fn][r] - mrow[r]);
          pm[fn][r] = p;
          rs[r] += p;
        }
#pragma unroll
      for (int r = 0; r < 4; r++) {
#pragma unroll
        for (int off = 1; off < 16; off <<= 1) rs[r] += __shfl_xor(rs[r], off);
        lrow[r] += rs[r];
      }
#pragma unroll
      for (int fn = 0; fn < 4; fn++)
#pragma unroll
        for (int r = 0; r < 4; r++) {
          int q = g4 * 4 + r;
          int chunk = (fn * 2 + (c16 >> 3)) ^ (q & 7);
          Pl[w][q * 64 + chunk * 8 + (c16 & 7)] = (bf16)pm[fn][r];
        }
      __builtin_amdgcn_s_setprio(1);
#pragma unroll
      for (int kk2 = 0; kk2 < 2; kk2++) {
        bf16x8 pf = *(const bf16x8*)(&Pl[w][c16 * 64 + ((kk2 * 4 + g4) ^ (c16 & 7)) * 8]);
#pragma unroll
        for (int fd = 0; fd < 16; fd++) {
          int rv = fd * 16 + c16;
          bf16x8 vf = *(const bf16x8*)(VsB + rv * 64 + ((kk2 * 4 + g4) ^ (c16 & 7)) * 8);
          acco[fd] = __builtin_amdgcn_mfma_f32_16x16x32_bf16(pf, vf, acco[fd], 0, 0, 0);
        }
      }
      __builtin_amdgcn_s_setprio(0);
      __syncthreads();
    }
    float inv[4];
#pragma unroll
    for (int r = 0; r < 4; r++) inv[r] = 1.0f / lrow[r];
#pragma unroll
    for (int fd = 0; fd < 16; fd++)
#pragma unroll
      for (int r = 0; r < 4; r++) {
        int qg = q0w + g4 * 4 + r;
        int col = h * HDIM + fd * 16 + c16;
        O[(size_t)qg * EMBED + col] = (bf16)(acco[fd][r] * inv[r]);
      }
  }
}

extern "C" void kernel_launch(void* const* d_in, const int* in_sizes, int n_in,
                              void* d_out, int out_size, void* d_ws, size_t ws_size,
                              hipStream_t stream) {
  const float* hidden = (const float*)d_in[0];
  const float* Wq = (const float*)d_in[1];
  const float* Wk = (const float*)d_in[2];
  const float* Wv = (const float*)d_in[3];
  const float* Wo = (const float*)d_in[4];
  float* out = (float*)d_out;

  char* ws = (char*)d_ws;
  const size_t SZ_H = (size_t)SLEN * EMBED * 2;   // 16 MiB
  const size_t SZ_W = (size_t)EMBED * EMBED * 2;  // 32 MiB
  if (ws_size < 5 * SZ_H + SZ_W) return;

  bf16* h_bf = (bf16*)ws;
  bf16* Wt   = (bf16*)(ws + SZ_H);
  bf16* Qb   = (bf16*)(ws + SZ_H + SZ_W);
  bf16* Kb   = (bf16*)(ws + 2 * SZ_H + SZ_W);
  bf16* Vtb  = (bf16*)(ws + 3 * SZ_H + SZ_W);
  bf16* Ob   = (bf16*)(ws + 4 * SZ_H + SZ_W);

  cast_kernel<<<(SLEN * EMBED / 4 + 255) / 256, 256, 0, stream>>>(hidden, h_bf,
                                                                  SLEN * EMBED / 4);

  dim3 tgrid(EMBED / 64, EMBED / 64);
  dim3 ggrid(EMBED / 256, SLEN / 128);  // 16 x 16 = 256 blocks

  transpose_cast<<<tgrid, 256, 0, stream>>>(Wq, Wt);
  gemm_pipe<1><<<ggrid, 512, 0, stream>>>(h_bf, Wt, Qb, SLEN, EMBED, EMBED);

  transpose_cast<<<tgrid, 256, 0, stream>>>(Wk, Wt);
  gemm_pipe<1><<<ggrid, 512, 0, stream>>>(h_bf, Wt, Kb, SLEN, EMBED, EMBED);

  transpose_cast<<<tgrid, 256, 0, stream>>>(Wv, Wt);
  gemm_pipe<2><<<ggrid, 512, 0, stream>>>(h_bf, Wt, Vtb, SLEN, EMBED, EMBED);

  attn_kernel<<<dim3(256), 256, 0, stream>>>(Qb, Kb, Vtb, Ob);

  transpose_cast<<<tgrid, 256, 0, stream>>>(Wo, Wt);
  gemm_pipe<3><<<ggrid, 512, 0, stream>>>(Ob, Wt, out, SLEN, EMBED, EMBED);
}